// Round 17
// baseline (1062.658 us; speedup 1.0000x reference)
//
#include <hip/hip_runtime.h>
#include <math.h>

typedef __attribute__((ext_vector_type(8))) short s8v;   // 8 bf16
typedef __attribute__((ext_vector_type(4))) float f4v;   // mfma acc

__device__ inline ushort f2bf(float x) {
    unsigned u = __float_as_uint(x);
    unsigned r = (u + 0x7FFFu + ((u >> 16) & 1u)) >> 16;   // RNE
    return (ushort)r;
}
__device__ inline float bf2f(ushort h) { return __uint_as_float(((unsigned)h) << 16); }
__device__ inline float sig_of(double n2) { return (float)(n2 / (sqrt(n2) + 1e-8)); }

#define DEV __global__ __launch_bounds__(256)

// ---------------------------------------------------------------- spectral norm, parallel (fp64)
struct SnMeta { const float* w[12]; int O[12]; int M[12]; };
struct SnRMap { short mat[85]; short row0[85]; };

DEV void snv2_kernel(SnMeta a, SnRMap mp, double* __restrict__ vbufraw) {
    int b = blockIdx.x;
    int id = mp.mat[b];
    int r0 = mp.row0[b];
    int O = a.O[id], M = a.M[id];
    int rend = min(r0 + 32, O);
    const float* W = a.w[id];
    for (int m = threadIdx.x; m < M; m += 256) {
        double s = 0.0;
        for (int o = r0; o < rend; ++o) s += (double)W[(size_t)o * M + m];
        atomicAdd(vbufraw + id * 2304 + m, s);
    }
}

DEV void snn_kernel(SnMeta a, const double* __restrict__ vbufraw, double* __restrict__ vnorm2) {
    int id = blockIdx.x;
    int M = a.M[id];
    double u0 = 1.0 / sqrt((double)a.O[id]);
    __shared__ double red[256];
    double ps = 0.0;
    for (int m = threadIdx.x; m < M; m += 256) { double v = vbufraw[id * 2304 + m] * u0; ps += v * v; }
    red[threadIdx.x] = ps; __syncthreads();
    for (int st = 128; st > 0; st >>= 1) { if (threadIdx.x < st) red[threadIdx.x] += red[threadIdx.x + st]; __syncthreads(); }
    if (threadIdx.x == 0) vnorm2[id] = red[0];
}

DEV void snu_kernel(SnMeta a, const double* __restrict__ vbufraw,
                    const double* __restrict__ vnorm2, double* __restrict__ unorm2) {
    int wv = blockIdx.x * 4 + (threadIdx.x >> 6);
    int lane = threadIdx.x & 63;
    const int cumR[13] = {0, 256, 512, 768, 1024, 1280, 1536, 1792, 2048, 2304, 2560, 2561, 2661};
    if (wv >= 2661) return;
    int id = 0;
    for (int i = 0; i < 12; ++i) if (wv >= cumR[i]) id = i;
    int o = wv - cumR[id];
    int M = a.M[id];
    double u0 = 1.0 / sqrt((double)a.O[id]);
    const float* Wr = a.w[id] + (size_t)o * M;
    const double* vb = vbufraw + id * 2304;
    double s = 0.0;
    for (int m = lane; m < M; m += 64) s += (double)Wr[m] * vb[m];
    for (int off = 32; off > 0; off >>= 1) s += __shfl_down(s, off, 64);
    if (lane == 0) {
        double s1 = 1.0 / (sqrt(vnorm2[id]) + 1e-8);
        double u = s * u0 * s1;
        atomicAdd(unorm2 + id, u * u);
    }
}

// ---------------------------------------------------------------- prep_all: weight prep + codebook norms (float) + codebook split
struct PrepArgs {
    const float* w[8]; int C[8]; int sigidx[8]; int outoff[8]; int nel[8];
    const float* cb[4];
};

DEV void prep_all_kernel(PrepArgs a, const double* __restrict__ unorm2,
                         ushort* __restrict__ wp, ushort* __restrict__ ep,
                         float* __restrict__ en) {
    int blk = blockIdx.x;
    if (blk < 1824) {
        int gid = blk * 256 + threadIdx.x;   // over sum(nel/9) = 466944
        int L = 0, cum = 0;
        for (int i = 0; i < 8; ++i) { int n9 = a.nel[i] / 9; if (gid >= cum && gid < cum + n9) { L = i; break; } cum += a.nel[i] / 9; }
        if (gid >= cum + a.nel[L] / 9) return;
        int e9 = gid - cum;
        if (L == 0) {
            int oc = e9 >> 5, k = e9 & 31;
            float inv = 1.f / sig_of(unorm2[0]);
            float v = 0.f;
            if (k < 27) v = a.w[0][((size_t)(oc * 3 + (k % 3))) * 9 + (k / 3)] * inv;
            ushort h = f2bf(v);
            ushort l = f2bf(v - bf2f(h));
            wp[oc * 32 + k] = h;
            wp[8192 + oc * 32 + k] = l;
            return;
        }
        int C = a.C[L];
        int NICC = (C + 31) >> 5;
        int icl = e9 & 31;
        int oc = (e9 >> 5) & 255;
        int icc = e9 >> 13;
        int ic = icc * 32 + icl;
        float inv = 1.f / sig_of(unorm2[a.sigidx[L]]);
        const float* wr = (ic < C) ? (a.w[L] + ((size_t)oc * C + ic) * 9) : nullptr;
        int nel = a.nel[L];
        int base = a.outoff[L] + icc * 8192 + oc * 32 + icl;
        #pragma unroll
        for (int tap = 0; tap < 9; ++tap) {
            float v = wr ? wr[tap] * inv : 0.f;
            ushort h = f2bf(v);
            ushort l = f2bf(v - bf2f(h));
            int o = base + tap * NICC * 8192;
            wp[o] = h;
            wp[o + nel] = l;
        }
    } else if (blk < 1824 + 4096) {
        int gid = (blk - 1824) * 256 + threadIdx.x;    // 0..1048575
        int layer = gid >> 18;
        int e = gid & 262143;
        int c5 = e & 31, k = (e >> 5) & 1023, icc = e >> 15;
        float v = a.cb[layer][(size_t)(icc * 32 + c5) * 1024 + k];
        ushort h = f2bf(v);
        ushort l = f2bf(v - bf2f(h));
        size_t o = (size_t)layer * 524288 + ((size_t)icc * 1024 + k) * 64 + c5;
        ep[o] = h; ep[o + 32] = l;
    } else {
        int b2 = blk - 1824 - 4096;
        int cc = b2 & 7, layer = b2 >> 3;
        const float* cb = a.cb[layer];
        int t = threadIdx.x;
        double d[4] = {};
        for (int c = cc * 32; c < cc * 32 + 32; ++c) {
            #pragma unroll
            for (int j = 0; j < 4; ++j) {
                double v = (double)cb[(size_t)c * 1024 + t + j * 256];
                d[j] += v * v;
            }
        }
        #pragma unroll
        for (int j = 0; j < 4; ++j) atomicAdd(en + layer * 1024 + t + j * 256, (float)d[j]);
    }
}

// ---------------------------------------------------------------- conv0_1 K-compressed: K=32 im2col (27 real), one MFMA chunk
__global__ __launch_bounds__(256) void conv01k_kernel(
        const float* __restrict__ x, const ushort* __restrict__ wp0,
        const float* __restrict__ bias, ushort* __restrict__ outs) {
    __shared__ float sX[3][10][10];
    __shared__ ushort sI[64][72];
    int t = threadIdx.x, wid = t >> 6, lane = t & 63, quad = lane >> 4, l15 = lane & 15;
    int n = blockIdx.z;
    int tIdx = blockIdx.x;
    int th0 = (tIdx >> 2) * 8, tw0 = (tIdx & 3) * 8;
    for (int i = t; i < 300; i += 256) {
        int ch = i / 100, r = i - (i / 100) * 100;
        int yy = r / 10, xx = r - (r / 10) * 10;
        int gy = th0 - 1 + yy, gx = tw0 - 1 + xx;
        float v = 0.f;
        if (gy >= 0 && gy < 32 && gx >= 0 && gx < 32) v = x[(((size_t)n * 3 + ch) * 32 + gy) * 32 + gx];
        sX[ch][yy][xx] = v;
    }
    __syncthreads();
    for (int i = t; i < 2048; i += 256) {
        int px = i >> 5, k = i & 31;
        float v = 0.f;
        if (k < 27) {
            int tap = k / 3, ch = k - tap * 3;
            int ty = tap / 3, tx = tap - ty * 3;
            v = sX[ch][(px >> 3) + ty][(px & 7) + tx];
        }
        ushort hv = f2bf(v);
        sI[px][k] = hv;
        sI[px][32 + k] = f2bf(v - bf2f(hv));
    }
    __syncthreads();
    int ocb = wid * 64;
    f4v acc[4][4];
    #pragma unroll
    for (int mt = 0; mt < 4; ++mt)
        #pragma unroll
        for (int nt = 0; nt < 4; ++nt) acc[mt][nt] = (f4v){0.f, 0.f, 0.f, 0.f};
    s8v ah[4], al[4], bh[4], bl[4];
    #pragma unroll
    for (int mt = 0; mt < 4; ++mt) {
        ah[mt] = *(const s8v*)&sI[mt * 16 + l15][quad * 8];
        al[mt] = *(const s8v*)&sI[mt * 16 + l15][32 + quad * 8];
    }
    #pragma unroll
    for (int nt = 0; nt < 4; ++nt) {
        int oc = ocb + nt * 16 + l15;
        bh[nt] = *(const s8v*)(wp0 + oc * 32 + quad * 8);
        bl[nt] = *(const s8v*)(wp0 + 8192 + oc * 32 + quad * 8);
    }
    #pragma unroll
    for (int mt = 0; mt < 4; ++mt)
        #pragma unroll
        for (int nt = 0; nt < 4; ++nt) {
            acc[mt][nt] = __builtin_amdgcn_mfma_f32_16x16x32_bf16(al[mt], bh[nt], acc[mt][nt], 0, 0, 0);
            acc[mt][nt] = __builtin_amdgcn_mfma_f32_16x16x32_bf16(ah[mt], bl[nt], acc[mt][nt], 0, 0, 0);
            acc[mt][nt] = __builtin_amdgcn_mfma_f32_16x16x32_bf16(ah[mt], bh[nt], acc[mt][nt], 0, 0, 0);
        }
    #pragma unroll
    for (int nt = 0; nt < 4; ++nt) {
        int oc = ocb + nt * 16 + l15;
        float bv = bias[oc];
        int iccg = oc >> 5, ocw = oc & 31;
        #pragma unroll
        for (int mt = 0; mt < 4; ++mt) {
            #pragma unroll
            for (int r = 0; r < 4; ++r) {
                int px = mt * 16 + quad * 4 + r;
                int y = th0 + (px >> 3), xx = tw0 + (px & 7);
                float v = fmaxf(acc[mt][nt][r] + bv, 0.f);
                ushort h = f2bf(v);
                size_t ob = ((((size_t)n * 32 + y) * 32 + xx) * 8 + iccg) * 64;
                outs[ob + ocw] = h;
                outs[ob + 32 + ocw] = f2bf(v - bf2f(h));
            }
        }
    }
}

// ---------------------------------------------------------------- VQ via MFMA, PX pixels per block
// hps (split-NHWC pre-relu) input path: vectorized staging; exact distance reconstructs hi+lo from LDS.
template<int PX>
DEV void vq2_kernel(const float* __restrict__ h, const ushort* __restrict__ hps,
                    const float* __restrict__ cb,
                    const ushort* __restrict__ ep, const float* __restrict__ en,
                    float* __restrict__ dacc, int* __restrict__ hist,
                    ushort* __restrict__ hs, int HW) {
    const int MT = PX / 16;
    const int SUBS = 256 / PX;
    __shared__ ushort sA[8 * PX * 66];
    __shared__ unsigned long long sKey[PX][65];
    __shared__ int sKst[PX];
    __shared__ float sPart[PX][SUBS];
    __shared__ double sSum[PX];
    int t = threadIdx.x, wid = t >> 6, lane = t & 63, quad = lane >> 4, l15 = lane & 15;
    int pix0 = blockIdx.x * PX, n = pix0 / HW, s0 = pix0 % HW;
    const float* hb = h ? (h + (size_t)n * 256 * HW + s0) : nullptr;

    if (hps) {
        for (int i = t; i < PX * 64; i += 256) {
            int p = i >> 6, rem = i & 63, icc = rem >> 3, part = rem & 7;
            size_t src = ((size_t)(n * HW + s0 + p) * 8 + icc) * 64 + part * 8;
            *(s8v*)&sA[icc * (PX * 66) + p * 66 + part * 8] = *(const s8v*)(hps + src);
        }
    } else {
        for (int i = t; i < 256 * PX; i += 256) {
            int c = i / PX, p = i % PX;
            float v = hb[(size_t)c * HW + p];
            ushort hv = f2bf(v), lv = f2bf(v - bf2f(hv));
            int a = (c >> 5) * (PX * 66) + p * 66 + (c & 31);
            sA[a] = hv; sA[a + 32] = lv;
        }
    }
    __syncthreads();

    if (hs) {   // relu'd split-NHWC copy
        for (int i = t; i < PX * 32; i += 256) {
            int p = i >> 5; int rem = i & 31; int icc = rem >> 2, q = rem & 3;
            int aoff = icc * (PX * 66) + p * 66 + q * 8;
            s8v hv = *(const s8v*)&sA[aoff];
            s8v lv = *(const s8v*)&sA[aoff + 32];
            #pragma unroll
            for (int j = 0; j < 8; ++j) {
                float f = bf2f((ushort)hv[j]) + bf2f((ushort)lv[j]);
                if (f <= 0.f) { hv[j] = 0; lv[j] = 0; }
            }
            size_t ob = (((size_t)n * HW + s0 + p) * 8 + icc) * 64 + q * 8;
            *(s8v*)(hs + ob) = hv;
            *(s8v*)(hs + ob + 32) = lv;
        }
    }

    unsigned long long best[MT][4];
    #pragma unroll
    for (int mt = 0; mt < MT; ++mt)
        #pragma unroll
        for (int r = 0; r < 4; ++r) best[mt][r] = ~0ull;

    for (int kp = 0; kp < 2; ++kp) {
        f4v acc[MT][8];
        #pragma unroll
        for (int mt = 0; mt < MT; ++mt)
            #pragma unroll
            for (int nt = 0; nt < 8; ++nt) acc[mt][nt] = (f4v){0.f, 0.f, 0.f, 0.f};
        for (int icc = 0; icc < 8; ++icc) {
            #pragma unroll
            for (int ntc = 0; ntc < 2; ++ntc) {
                s8v eh[4], el[4];
                #pragma unroll
                for (int j = 0; j < 4; ++j) {
                    int k = wid * 256 + kp * 128 + (ntc * 4 + j) * 16 + l15;
                    const ushort* q = ep + ((size_t)icc * 1024 + k) * 64 + quad * 8;
                    eh[j] = *(const s8v*)q; el[j] = *(const s8v*)(q + 32);
                }
                #pragma unroll
                for (int mt = 0; mt < MT; ++mt) {
                    int a = icc * (PX * 66) + (mt * 16 + l15) * 66 + quad * 8;
                    s8v ah = *(const s8v*)&sA[a], al = *(const s8v*)&sA[a + 32];
                    #pragma unroll
                    for (int j = 0; j < 4; ++j) {
                        int nt = ntc * 4 + j;
                        acc[mt][nt] = __builtin_amdgcn_mfma_f32_16x16x32_bf16(al, eh[j], acc[mt][nt], 0, 0, 0);
                        acc[mt][nt] = __builtin_amdgcn_mfma_f32_16x16x32_bf16(ah, el[j], acc[mt][nt], 0, 0, 0);
                        acc[mt][nt] = __builtin_amdgcn_mfma_f32_16x16x32_bf16(ah, eh[j], acc[mt][nt], 0, 0, 0);
                    }
                }
            }
        }
        #pragma unroll
        for (int mt = 0; mt < MT; ++mt)
            #pragma unroll
            for (int nt = 0; nt < 8; ++nt) {
                int k = wid * 256 + kp * 128 + nt * 16 + l15;
                float ev = en[k];
                #pragma unroll
                for (int r = 0; r < 4; ++r) {
                    float s = ev - 2.f * acc[mt][nt][r];
                    unsigned ub = __float_as_uint(s);
                    ub = ((int)ub < 0) ? ~ub : (ub | 0x80000000u);
                    unsigned long long key = ((unsigned long long)ub << 32) | (unsigned)k;
                    if (key < best[mt][r]) best[mt][r] = key;
                }
            }
    }
    #pragma unroll
    for (int mt = 0; mt < MT; ++mt)
        #pragma unroll
        for (int r = 0; r < 4; ++r) {
            int p = mt * 16 + quad * 4 + r;
            sKey[p][wid * 16 + l15] = best[mt][r];
        }
    __syncthreads();
    if (t < PX) {
        unsigned long long m = ~0ull;
        for (int j = 0; j < 64; ++j) { unsigned long long v = sKey[t][j]; if (v < m) m = v; }
        sKst[t] = (int)(unsigned)(m & 0xFFFFFFFFu);
    }
    __syncthreads();
    {   // exact direct-form distance for selected code
        int p = t % PX, sub = t / PX;
        int ks = sKst[p];
        const float* ec = cb + ks;
        float d = 0.f;
        for (int c = sub * PX; c < sub * PX + PX; ++c) {
            float xv;
            if (hps) {
                int a = (c >> 5) * (PX * 66) + p * 66 + (c & 31);
                xv = bf2f(sA[a]) + bf2f(sA[a + 32]);
            } else {
                xv = hb[(size_t)c * HW + p];
            }
            float evv = ec[(size_t)c * 1024];
            float df = xv - evv;
            d += df * df;
        }
        sPart[p][sub] = d;
    }
    __syncthreads();
    if (t < PX) {
        float s = 0.f;
        for (int j = 0; j < SUBS; ++j) s += sPart[t][j];
        sSum[t] = (double)s;
        if (hist) atomicAdd(hist + sKst[t], 1);
    }
    __syncthreads();
    if (t == 0) {
        double s = 0.0;
        for (int i = 0; i < PX; ++i) s += sSum[i];
        atomicAdd(dacc + n, (float)s);
    }
}

// ---------------------------------------------------------------- 16x16x32 MFMA implicit-GEMM 3x3 conv, pad 1
// INS: register-prefetch + LDS ping-pong. POOL+OUTS: pooled output written pre-relu split-NHWC (h1ps).
template<int ST, int NW, int NTW, int NICC, bool RELU, bool POOL, bool RES, bool INS, bool OUTS, bool SC0>
__global__ __launch_bounds__(NW * 64) void conv_mfma(
        const float* __restrict__ in, const ushort* __restrict__ ins,
        const ushort* __restrict__ wp, const float* __restrict__ bias,
        const float* __restrict__ res, float* __restrict__ out,
        ushort* __restrict__ outs, int C, int H,
        const float* __restrict__ scw, const float* __restrict__ scb,
        const double* __restrict__ un2) {
    const int MT = ST * 4;
    const int PLANE = NICC * 73728;
    const int SASZ = ST * 100 * 72;
    const int NITER = (ST * 100 * 8 + NW * 64 - 1) / (NW * 64);
    __shared__ ushort sA[(INS ? 2 : 1) * SASZ];
    __shared__ float sSC[3][16];
    int t = threadIdx.x;
    int wid = t >> 6, lane = t & 63, quad = lane >> 4, l15 = lane & 15;
    int n = blockIdx.z;
    int ocb = blockIdx.y * (NW * NTW * 16) + wid * (NTW * 16);
    int tpr = H >> 3;
    int tIdx0 = blockIdx.x * ST;

    int abase[MT];
    #pragma unroll
    for (int mt = 0; mt < MT; ++mt) {
        int m64 = (mt & 3) * 16 + l15;
        abase[mt] = (((mt >> 2) * 100 + (m64 >> 3) * 10 + (m64 & 7)) * 72) + quad * 8;
    }

    unsigned gofs[INS ? NITER : 1];
    s8v pref[INS ? NITER : 1];
    if (INS) {
        #pragma unroll
        for (int it = 0; it < NITER; ++it) {
            int i = t + it * NW * 64;
            gofs[it] = 0xFFFFFFFFu;
            if (i < ST * 100 * 8) {
                int pg = i >> 3, part = i & 7;
                int tile = pg / 100, pos = pg - tile * 100;
                int tIdx = tIdx0 + tile;
                int th0 = (tIdx / tpr) * 8, tw0 = (tIdx % tpr) * 8;
                int gy = th0 - 1 + pos / 10, gx = tw0 - 1 + (pos % 10);
                if (gy >= 0 && gy < H && gx >= 0 && gx < H)
                    gofs[it] = (unsigned)((((n * H + gy) * H + gx) * 8) * 64 + part * 8);
            }
        }
        #pragma unroll
        for (int it = 0; it < NITER; ++it)
            pref[it] = (gofs[it] != 0xFFFFFFFFu) ? *(const s8v*)(ins + gofs[it])
                                                 : (s8v){0, 0, 0, 0, 0, 0, 0, 0};
        #pragma unroll
        for (int it = 0; it < NITER; ++it) {
            int i = t + it * NW * 64;
            if (i < ST * 100 * 8) *(s8v*)(&sA[(i >> 3) * 72 + (i & 7) * 8]) = pref[it];
        }
        if (NICC > 1) {
            #pragma unroll
            for (int it = 0; it < NITER; ++it)
                pref[it] = (gofs[it] != 0xFFFFFFFFu) ? *(const s8v*)(ins + gofs[it] + 64)
                                                     : (s8v){0, 0, 0, 0, 0, 0, 0, 0};
        }
        __syncthreads();
    }

    f4v acc[MT][NTW];
    #pragma unroll
    for (int mt = 0; mt < MT; ++mt)
        #pragma unroll
        for (int nt = 0; nt < NTW; ++nt)
            acc[mt][nt] = (f4v){0.f, 0.f, 0.f, 0.f};

    for (int icc = 0; icc < NICC; ++icc) {
        int bufbase = INS ? (icc & 1) * SASZ : 0;
        if (INS) {
            if (icc + 1 < NICC) {
                int nb = ((icc + 1) & 1) * SASZ;
                #pragma unroll
                for (int it = 0; it < NITER; ++it) {
                    int i = t + it * NW * 64;
                    if (i < ST * 100 * 8) *(s8v*)(&sA[nb + (i >> 3) * 72 + (i & 7) * 8]) = pref[it];
                }
                if (icc + 2 < NICC) {
                    #pragma unroll
                    for (int it = 0; it < NITER; ++it)
                        pref[it] = (gofs[it] != 0xFFFFFFFFu) ? *(const s8v*)(ins + gofs[it] + (unsigned)(icc + 2) * 64)
                                                             : (s8v){0, 0, 0, 0, 0, 0, 0, 0};
                }
            }
        } else {
            __syncthreads();
            for (int i = t; i < ST * 100 * 32; i += NW * 64) {
                int ic = i / (ST * 100);
                int rr = i - ic * (ST * 100);
                int tile = rr / 100, pos = rr - (rr / 100) * 100;
                int tIdx = tIdx0 + tile;
                int th0 = (tIdx / tpr) * 8, tw0 = (tIdx % tpr) * 8;
                int gy = th0 - 1 + pos / 10, gx = tw0 - 1 + (pos % 10);
                int gic = icc * 32 + ic;
                ushort hv = 0, lv = 0;
                if (gic < C && gy >= 0 && gy < H && gx >= 0 && gx < H) {
                    float v = in[(((size_t)n * C + gic) * H + gy) * H + gx];
                    if (RELU) v = fmaxf(v, 0.f);
                    hv = f2bf(v);
                    lv = f2bf(v - bf2f(hv));
                }
                int si = (tile * 100 + pos) * 72 + ic;
                sA[si] = hv; sA[si + 32] = lv;
            }
            __syncthreads();
        }

        s8v bh[2][NTW], bl[2][NTW];
        {
            size_t wb = (size_t)icc * 8192;
            #pragma unroll
            for (int nt = 0; nt < NTW; ++nt) {
                size_t wo = wb + (size_t)(ocb + nt * 16 + l15) * 32 + quad * 8;
                bh[0][nt] = *(const s8v*)(wp + wo);
                bl[0][nt] = *(const s8v*)(wp + PLANE + wo);
            }
        }
        #pragma unroll
        for (int tap = 0; tap < 9; ++tap) {
            int cb = tap & 1;
            if (tap < 8) {
                size_t wb = (size_t)((tap + 1) * NICC + icc) * 8192;
                #pragma unroll
                for (int nt = 0; nt < NTW; ++nt) {
                    size_t wo = wb + (size_t)(ocb + nt * 16 + l15) * 32 + quad * 8;
                    bh[cb ^ 1][nt] = *(const s8v*)(wp + wo);
                    bl[cb ^ 1][nt] = *(const s8v*)(wp + PLANE + wo);
                }
            }
            int toff = ((tap / 3) * 10 + (tap % 3)) * 72;
            #pragma unroll
            for (int mt = 0; mt < MT; ++mt) {
                s8v ah = *(const s8v*)(&sA[bufbase + abase[mt] + toff]);
                s8v al = *(const s8v*)(&sA[bufbase + abase[mt] + toff + 32]);
                #pragma unroll
                for (int nt = 0; nt < NTW; ++nt) {
                    acc[mt][nt] = __builtin_amdgcn_mfma_f32_16x16x32_bf16(al, bh[cb][nt], acc[mt][nt], 0, 0, 0);
                    acc[mt][nt] = __builtin_amdgcn_mfma_f32_16x16x32_bf16(ah, bl[cb][nt], acc[mt][nt], 0, 0, 0);
                    acc[mt][nt] = __builtin_amdgcn_mfma_f32_16x16x32_bf16(ah, bh[cb][nt], acc[mt][nt], 0, 0, 0);
                }
            }
        }
        if (INS && icc + 1 < NICC) __syncthreads();
    }

    if (SC0) {
        __syncthreads();
        if (t < 48) {
            int ic = t >> 4, p = t & 15;
            int py = p >> 2, px = p & 3;
            int th0 = (tIdx0 / tpr) * 8, tw0 = (tIdx0 % tpr) * 8;
            const float* xb = in + (((size_t)(n * 3 + ic)) * 32 + th0 + 2 * py) * 32 + tw0 + 2 * px;
            sSC[ic][p] = 0.25f * (xb[0] + xb[1] + xb[32] + xb[33]);
        }
        __syncthreads();
    }

    #pragma unroll
    for (int nt = 0; nt < NTW; ++nt) {
        int oc = ocb + nt * 16 + l15;
        float bv = bias[oc];
        #pragma unroll
        for (int mt = 0; mt < MT; ++mt) {
            int tIdx = tIdx0 + (mt >> 2);
            int th0 = (tIdx / tpr) * 8, tw0 = (tIdx % tpr) * 8;
            if (POOL) {
                float s01 = acc[mt][nt][0] + acc[mt][nt][1];
                float s23 = acc[mt][nt][2] + acc[mt][nt][3];
                float o01 = s01 + __shfl_down(s01, 32, 64);
                float o23 = s23 + __shfl_down(s23, 32, 64);
                if (quad < 2) {
                    int Ho = H >> 1;
                    int oy = (th0 >> 1) + (mt & 3);
                    int ox = (tw0 >> 1) + quad * 2;
                    float v0 = 0.25f * o01 + bv;
                    float v1 = 0.25f * o23 + bv;
                    if (SC0) {
                        int p0 = (mt & 3) * 4 + quad * 2;
                        float scale = 1.f / sig_of(un2[2]);
                        float sa0 = scb[oc], sa1 = scb[oc];
                        #pragma unroll
                        for (int ic = 0; ic < 3; ++ic) {
                            float wv = scw[oc * 3 + ic] * scale;
                            sa0 += sSC[ic][p0] * wv;
                            sa1 += sSC[ic][p0 + 1] * wv;
                        }
                        v0 += sa0;
                        v1 += sa1;
                    }
                    if (OUTS) {   // pre-relu split-NHWC pooled output (h1ps)
                        int iccg = oc >> 5, ocw = oc & 31;
                        size_t ob0 = ((((size_t)n * Ho + oy) * Ho + ox) * 8 + iccg) * 64;
                        size_t ob1 = ((((size_t)n * Ho + oy) * Ho + ox + 1) * 8 + iccg) * 64;
                        ushort h0 = f2bf(v0), h1v = f2bf(v1);
                        outs[ob0 + ocw] = h0;
                        outs[ob0 + 32 + ocw] = f2bf(v0 - bf2f(h0));
                        outs[ob1 + ocw] = h1v;
                        outs[ob1 + 32 + ocw] = f2bf(v1 - bf2f(h1v));
                    } else {
                        size_t ob = ((size_t)(n * 256 + oc) * Ho + oy) * Ho;
                        out[ob + ox] = v0;
                        out[ob + ox + 1] = v1;
                    }
                }
            } else if (OUTS) {
                int iccg = oc >> 5, ocw = oc & 31;
                #pragma unroll
                for (int r = 0; r < 4; ++r) {
                    int p16 = quad * 4 + r;
                    int y = th0 + (mt & 3) * 2 + (p16 >> 3);
                    int x = tw0 + (p16 & 7);
                    float v = fmaxf(acc[mt][nt][r] + bv, 0.f);
                    ushort h = f2bf(v);
                    size_t ob = ((((size_t)n * H + y) * H + x) * 8 + iccg) * 64;
                    outs[ob + ocw] = h;
                    outs[ob + 32 + ocw] = f2bf(v - bf2f(h));
                }
            } else {
                #pragma unroll
                for (int r = 0; r < 4; ++r) {
                    int p16 = quad * 4 + r;
                    int y = th0 + (mt & 3) * 2 + (p16 >> 3);
                    int x = tw0 + (p16 & 7);
                    size_t oi = (((size_t)(n * 256 + oc)) * H + y) * H + x;
                    float v = acc[mt][nt][r] + bv;
                    if (RES) v += res[oi];
                    out[oi] = v;
                }
            }
        }
    }
}

// ---------------------------------------------------------------- block-1 shortcut: h2 += conv1x1(pool2(h1)) + b ; h1 from h1ps (hi+lo)
DEV void sc1_kernel(const ushort* __restrict__ h1ps, const float* __restrict__ wsc,
                    const float* __restrict__ bsc, const double* __restrict__ unorm2,
                    float* __restrict__ h2) {
    __shared__ float sP[64][64];
    __shared__ float sWs[64][65];
    int t = threadIdx.x;
    int n = blockIdx.x, ocb = blockIdx.y * 64;
    int ocg = t & 15, pgr = t >> 4;
    float scale = 1.f / sig_of(unorm2[5]);
    float acc[4][4] = {};
    for (int c0 = 0; c0 < 256; c0 += 64) {
        __syncthreads();
        for (int i = t; i < 4096; i += 256) {
            int ic = i >> 6, p = i & 63;
            int oh = p >> 3, ow = p & 7;
            int cch = c0 + ic;
            int cg = (cch >> 5) * 64 + (cch & 31);
            float s = 0.f;
            #pragma unroll
            for (int dy = 0; dy < 2; ++dy)
                #pragma unroll
                for (int dx = 0; dx < 2; ++dx) {
                    int pix = (oh * 2 + dy) * 16 + ow * 2 + dx;
                    size_t a = ((size_t)(n * 256 + pix)) * 512 + cg;
                    s += bf2f(h1ps[a]) + bf2f(h1ps[a + 32]);
                }
            sP[ic][p] = 0.25f * s;
            int oc = i >> 6, ic2 = i & 63;
            sWs[oc][ic2] = wsc[(size_t)(ocb + oc) * 256 + c0 + ic2] * scale;
        }
        __syncthreads();
        for (int ic = 0; ic < 64; ++ic) {
            float pv[4];
            #pragma unroll
            for (int q = 0; q < 4; ++q) pv[q] = sP[ic][pgr * 4 + q];
            #pragma unroll
            for (int j = 0; j < 4; ++j) {
                float wv = sWs[ocg + 16 * j][ic];
                #pragma unroll
                for (int q = 0; q < 4; ++q) acc[j][q] += wv * pv[q];
            }
        }
    }
    #pragma unroll
    for (int j = 0; j < 4; ++j) {
        int oc = ocb + ocg + 16 * j;
        float bv = bsc[oc];
        #pragma unroll
        for (int q = 0; q < 4; ++q) {
            size_t oi = ((size_t)(n * 256 + oc)) * 64 + pgr * 4 + q;
            h2[oi] += acc[j][q] + bv;
        }
    }
}

// ---------------------------------------------------------------- head + ppl (merged)
DEV void headppl_kernel(const float* __restrict__ h4, const float* __restrict__ lin_w,
                        const float* __restrict__ lin_b, const float* __restrict__ emb_w,
                        const int* __restrict__ y, const double* __restrict__ unorm2,
                        const float* __restrict__ dacc, const int* __restrict__ hist,
                        float* __restrict__ out) {
    __shared__ double r1[256], r2[256];
    int b = blockIdx.x, t = threadIdx.x;
    const float* hb = h4 + ((size_t)b * 256 + t) * 64;
    float s = 0.f;
    #pragma unroll 4
    for (int i = 0; i < 64; ++i) s += fmaxf(hb[i], 0.f);
    int yb = y[b];
    r1[t] = (double)s * (double)lin_w[t];
    r2[t] = (double)s * (double)emb_w[(size_t)yb * 256 + t];
    __syncthreads();
    for (int st = 128; st > 0; st >>= 1) { if (t < st) { r1[t] += r1[t + st]; r2[t] += r2[t + st]; } __syncthreads(); }
    if (t == 0) {
        out[b] = (float)(r1[0] / (double)sig_of(unorm2[10]) + (double)lin_b[0] + r2[0] / (double)sig_of(unorm2[11]));
        out[64 + b] = (float)(0.5 * ((double)dacc[b] * (1.0 / 65536.0)
                              + ((double)dacc[64 + b] + (double)dacc[128 + b] + (double)dacc[192 + b]) * (1.0 / 16384.0)));
    }
    if (b == 0) {
        __syncthreads();
        double ps = 0.0;
        for (int k = t; k < 1024; k += 256) {
            double p = (double)hist[k] * (1.0 / 4096.0);
            ps += p * log(p + 1e-10);
        }
        r1[t] = ps; __syncthreads();
        for (int st = 128; st > 0; st >>= 1) { if (t < st) r1[t] += r1[t + st]; __syncthreads(); }
        if (t == 0) out[128] = (float)exp(-r1[0]);
    }
}

// ---------------------------------------------------------------- launch
extern "C" void kernel_launch(void* const* d_in, const int* in_sizes, int n_in,
                              void* d_out, int out_size, void* d_ws, size_t ws_size,
                              hipStream_t stream) {
    (void)in_sizes; (void)n_in; (void)out_size; (void)ws_size;
    const float* x      = (const float*)d_in[0];
    const int*   y      = (const int*)  d_in[1];
    const float* b0_w1  = (const float*)d_in[2];
    const float* b0_b1  = (const float*)d_in[3];
    const float* b0_w2  = (const float*)d_in[4];
    const float* b0_b2  = (const float*)d_in[5];
    const float* b0_wsc = (const float*)d_in[6];
    const float* b0_bsc = (const float*)d_in[7];
    const float* b1_w1  = (const float*)d_in[8];
    const float* b1_b1  = (const float*)d_in[9];
    const float* b1_w2  = (const float*)d_in[10];
    const float* b1_b2  = (const float*)d_in[11];
    const float* b1_wsc = (const float*)d_in[12];
    const float* b1_bsc = (const float*)d_in[13];
    const float* b2_w1  = (const float*)d_in[14];
    const float* b2_b1  = (const float*)d_in[15];
    const float* b2_w2  = (const float*)d_in[16];
    const float* b2_b2  = (const float*)d_in[17];
    const float* b3_w1  = (const float*)d_in[18];
    const float* b3_b1  = (const float*)d_in[19];
    const float* b3_w2  = (const float*)d_in[20];
    const float* b3_b2  = (const float*)d_in[21];
    const float* cb0    = (const float*)d_in[22];
    const float* cb1    = (const float*)d_in[23];
    const float* cb2    = (const float*)d_in[24];
    const float* cb3    = (const float*)d_in[25];
    const float* lin_w  = (const float*)d_in[26];
    const float* lin_b  = (const float*)d_in[27];
    const float* emb_w  = (const float*)d_in[28];
    float* out = (float*)d_out;

    // ---- workspace map (float indices) ----
    float* wsf  = (float*)d_ws;
    float* dacc = wsf + 16;                                      // [16,272)
    double* vnorm2 = (double*)(wsf + 512);                       // [512,536)
    double* unorm2 = (double*)(wsf + 544);                       // [544,568)
    int*   hist = (int*)(wsf + 1296);                            // [1296,2320) ints
    float* en   = wsf + 10752;                                   // [10752,14848)
    ushort* Aus  = (ushort*)(wsf + 65536);                       // [65536,16842752) (dead after conv0_2)
    ushort* tbus = (ushort*)(wsf + 65536);                       // aliases dead A
    ushort* t2us = (ushort*)(wsf + 4259840);
    ushort* h1s  = (ushort*)(wsf + 5308416);
    ushort* h2s  = (ushort*)(wsf + 9502720);
    ushort* h3s  = (ushort*)(wsf + 10551296);
    ushort* h1ps = (ushort*)(wsf + 16842752);                    // 8388608 ush = [16842752,21037056) f (pre-relu split h1)
    float* h2 = wsf + 21037056;
    float* h3 = h2 + 1048576;
    float* h4 = h3 + 1048576;
    ushort* wp = (ushort*)(wsf + 24182784);                      // ends f 28385280
    double* vbufraw = (double*)(wsf + 28385280);                 // ends f 28440576
    ushort* ep = (ushort*)(wsf + 28440576);                      // ends f 30537728 (116.5 MB)

    hipMemsetAsync(wsf, 0, 14848 * sizeof(float), stream);       // dacc, vnorm2, unorm2, hist, en
    hipMemsetAsync(vbufraw, 0, 27648 * sizeof(double), stream);

    SnMeta sm;
    const float* sw[12] = {b0_w1, b0_w2, b0_wsc, b1_w1, b1_w2, b1_wsc,
                           b2_w1, b2_w2, b3_w1, b3_w2, lin_w, emb_w};
    int sO[12] = {256, 256, 256, 256, 256, 256, 256, 256, 256, 256, 1, 100};
    int sM[12] = {27, 2304, 3, 2304, 2304, 256, 2304, 2304, 2304, 2304, 256, 256};
    for (int i = 0; i < 12; ++i) { sm.w[i] = sw[i]; sm.O[i] = sO[i]; sm.M[i] = sM[i]; }
    SnRMap rp;
    {
        int bi = 0;
        for (int i = 0; i < 12; ++i) {
            int nb = (sO[i] + 31) / 32;
            for (int j = 0; j < nb; ++j) { rp.mat[bi] = (short)i; rp.row0[bi] = (short)(j * 32); ++bi; }
        }
    }
    snv2_kernel<<<85, 256, 0, stream>>>(sm, rp, vbufraw);
    snn_kernel<<<12, 256, 0, stream>>>(sm, vbufraw, vnorm2);
    snu_kernel<<<666, 256, 0, stream>>>(sm, vbufraw, vnorm2, unorm2);

    PrepArgs pa;
    const float* pw[8] = {b0_w1, b0_w2, b1_w1, b1_w2, b2_w1, b2_w2, b3_w1, b3_w2};
    int pC[8]   = {3, 256, 256, 256, 256, 256, 256, 256};
    int pS[8]   = {0, 1, 3, 4, 6, 7, 8, 9};
    int pOff[8] = {0, 147456, 1327104, 2506752, 3686400, 4866048, 6045696, 7225344};
    int pN[8]   = {73728, 589824, 589824, 589824, 589824, 589824, 589824, 589824};
    for (int i = 0; i < 8; ++i) { pa.w[i] = pw[i]; pa.C[i] = pC[i]; pa.sigidx[i] = pS[i]; pa.outoff[i] = pOff[i]; pa.nel[i] = pN[i]; }
    pa.cb[0] = cb0; pa.cb[1] = cb1; pa.cb[2] = cb2; pa.cb[3] = cb3;
    prep_all_kernel<<<5952, 256, 0, stream>>>(pa, unorm2, wp, ep, en);

    // block 0: conv0_1 K-compressed; conv0_2 (fused sc0) -> h1ps (pre-relu split-NHWC)
    conv01k_kernel<<<dim3(16, 1, 64), 256, 0, stream>>>(x, wp, b0_b1, Aus);
    conv_mfma<1, 4, 2, 8, false, true, false, true, true, true><<<dim3(16, 2, 64), 256, 0, stream>>>(
        x, Aus, wp + 147456, b0_b2, nullptr, nullptr, h1ps, 256, 32, b0_wsc, b0_bsc, unorm2);
    vq2_kernel<32><<<512, 256, 0, stream>>>(nullptr, h1ps, cb0, ep + 0, en + 0, dacc + 0, nullptr, h1s, 256);

    // block 1
    conv_mfma<1, 4, 1, 8, false, false, false, true, true, false><<<dim3(4, 4, 64), 256, 0, stream>>>(
        nullptr, h1s, wp + 1327104, b1_b1, nullptr, nullptr, tbus, 256, 16, nullptr, nullptr, nullptr);
    conv_mfma<1, 4, 1, 8, false, true, false, true, false, false><<<dim3(4, 4, 64), 256, 0, stream>>>(
        nullptr, tbus, wp + 2506752, b1_b2, nullptr, h2, nullptr, 256, 16, nullptr, nullptr, nullptr);
    sc1_kernel<<<dim3(64, 4), 256, 0, stream>>>(h1ps, b1_wsc, b1_bsc, unorm2, h2);
    vq2_kernel<16><<<256, 256, 0, stream>>>(h2, nullptr, cb1, ep + 524288, en + 1024, dacc + 64, nullptr, h2s, 64);

    // block 2
    conv_mfma<1, 2, 1, 8, false, false, false, true, true, false><<<dim3(1, 8, 64), 128, 0, stream>>>(
        nullptr, h2s, wp + 3686400, b2_b1, nullptr, nullptr, t2us, 256, 8, nullptr, nullptr, nullptr);
    conv_mfma<1, 2, 1, 8, false, false, true, true, false, false><<<dim3(1, 8, 64), 128, 0, stream>>>(
        nullptr, t2us, wp + 4866048, b2_b2, h2, h3, nullptr, 256, 8, nullptr, nullptr, nullptr);
    vq2_kernel<16><<<256, 256, 0, stream>>>(h3, nullptr, cb2, ep + 1048576, en + 2048, dacc + 128, nullptr, h3s, 64);

    // block 3
    conv_mfma<1, 2, 1, 8, false, false, false, true, true, false><<<dim3(1, 8, 64), 128, 0, stream>>>(
        nullptr, h3s, wp + 6045696, b3_b1, nullptr, nullptr, t2us, 256, 8, nullptr, nullptr, nullptr);
    conv_mfma<1, 2, 1, 8, false, false, true, true, false, false><<<dim3(1, 8, 64), 128, 0, stream>>>(
        nullptr, t2us, wp + 7225344, b3_b2, h3, h4, nullptr, 256, 8, nullptr, nullptr, nullptr);
    vq2_kernel<16><<<256, 256, 0, stream>>>(h4, nullptr, cb3, ep + 1572864, en + 3072, dacc + 192, hist, nullptr, 64);

    headppl_kernel<<<64, 256, 0, stream>>>(h4, lin_w, lin_b, emb_w, y, unorm2, dacc, hist, out);
}

// Round 18
// 1037.966 us; speedup vs baseline: 1.0238x; 1.0238x over previous
//
#include <hip/hip_runtime.h>
#include <math.h>

typedef __attribute__((ext_vector_type(8))) short s8v;   // 8 bf16
typedef __attribute__((ext_vector_type(4))) float f4v;   // mfma acc

__device__ inline ushort f2bf(float x) {
    unsigned u = __float_as_uint(x);
    unsigned r = (u + 0x7FFFu + ((u >> 16) & 1u)) >> 16;   // RNE
    return (ushort)r;
}
__device__ inline float bf2f(ushort h) { return __uint_as_float(((unsigned)h) << 16); }
__device__ inline float sig_of(double n2) { return (float)(n2 / (sqrt(n2) + 1e-8)); }

#define DEV __global__ __launch_bounds__(256)

// ---------------------------------------------------------------- spectral norm, parallel (fp64)
struct SnMeta { const float* w[12]; int O[12]; int M[12]; };
struct SnRMap { short mat[85]; short row0[85]; };

DEV void snv2_kernel(SnMeta a, SnRMap mp, double* __restrict__ vbufraw) {
    int b = blockIdx.x;
    int id = mp.mat[b];
    int r0 = mp.row0[b];
    int O = a.O[id], M = a.M[id];
    int rend = min(r0 + 32, O);
    const float* W = a.w[id];
    for (int m = threadIdx.x; m < M; m += 256) {
        double s = 0.0;
        for (int o = r0; o < rend; ++o) s += (double)W[(size_t)o * M + m];
        atomicAdd(vbufraw + id * 2304 + m, s);
    }
}

DEV void snn_kernel(SnMeta a, const double* __restrict__ vbufraw, double* __restrict__ vnorm2) {
    int id = blockIdx.x;
    int M = a.M[id];
    double u0 = 1.0 / sqrt((double)a.O[id]);
    __shared__ double red[256];
    double ps = 0.0;
    for (int m = threadIdx.x; m < M; m += 256) { double v = vbufraw[id * 2304 + m] * u0; ps += v * v; }
    red[threadIdx.x] = ps; __syncthreads();
    for (int st = 128; st > 0; st >>= 1) { if (threadIdx.x < st) red[threadIdx.x] += red[threadIdx.x + st]; __syncthreads(); }
    if (threadIdx.x == 0) vnorm2[id] = red[0];
}

DEV void snu_kernel(SnMeta a, const double* __restrict__ vbufraw,
                    const double* __restrict__ vnorm2, double* __restrict__ unorm2) {
    int wv = blockIdx.x * 4 + (threadIdx.x >> 6);
    int lane = threadIdx.x & 63;
    const int cumR[13] = {0, 256, 512, 768, 1024, 1280, 1536, 1792, 2048, 2304, 2560, 2561, 2661};
    if (wv >= 2661) return;
    int id = 0;
    for (int i = 0; i < 12; ++i) if (wv >= cumR[i]) id = i;
    int o = wv - cumR[id];
    int M = a.M[id];
    double u0 = 1.0 / sqrt((double)a.O[id]);
    const float* Wr = a.w[id] + (size_t)o * M;
    const double* vb = vbufraw + id * 2304;
    double s = 0.0;
    for (int m = lane; m < M; m += 64) s += (double)Wr[m] * vb[m];
    for (int off = 32; off > 0; off >>= 1) s += __shfl_down(s, off, 64);
    if (lane == 0) {
        double s1 = 1.0 / (sqrt(vnorm2[id]) + 1e-8);
        double u = s * u0 * s1;
        atomicAdd(unorm2 + id, u * u);
    }
}

// ---------------------------------------------------------------- prep_all: weight prep + codebook norms + codebook split
// L0 (b0_w1, C=3) uses the K-compressed layout: wp0[oc*32 + k], k = tap*3 + ch (27 real, 5 zero); lo plane at +8192.
struct PrepArgs {
    const float* w[8]; int C[8]; int sigidx[8]; int outoff[8]; int nel[8];
    const float* cb[4];
};

DEV void prep_all_kernel(PrepArgs a, const double* __restrict__ unorm2,
                         ushort* __restrict__ wp, ushort* __restrict__ ep,
                         double* __restrict__ en64) {
    int blk = blockIdx.x;
    if (blk < 1824) {
        int gid = blk * 256 + threadIdx.x;   // over sum(nel/9) = 466944
        int L = 0, cum = 0;
        for (int i = 0; i < 8; ++i) { int n9 = a.nel[i] / 9; if (gid >= cum && gid < cum + n9) { L = i; break; } cum += a.nel[i] / 9; }
        if (gid >= cum + a.nel[L] / 9) return;
        int e9 = gid - cum;
        if (L == 0) {
            // K-compressed conv0_1 weights: thread per (oc, k)
            int oc = e9 >> 5, k = e9 & 31;
            float inv = 1.f / sig_of(unorm2[0]);
            float v = 0.f;
            if (k < 27) v = a.w[0][((size_t)(oc * 3 + (k % 3))) * 9 + (k / 3)] * inv;
            ushort h = f2bf(v);
            ushort l = f2bf(v - bf2f(h));
            wp[oc * 32 + k] = h;
            wp[8192 + oc * 32 + k] = l;
            return;
        }
        int C = a.C[L];
        int NICC = (C + 31) >> 5;
        int icl = e9 & 31;
        int oc = (e9 >> 5) & 255;
        int icc = e9 >> 13;
        int ic = icc * 32 + icl;
        float inv = 1.f / sig_of(unorm2[a.sigidx[L]]);
        const float* wr = (ic < C) ? (a.w[L] + ((size_t)oc * C + ic) * 9) : nullptr;
        int nel = a.nel[L];
        int base = a.outoff[L] + icc * 8192 + oc * 32 + icl;
        #pragma unroll
        for (int tap = 0; tap < 9; ++tap) {
            float v = wr ? wr[tap] * inv : 0.f;
            ushort h = f2bf(v);
            ushort l = f2bf(v - bf2f(h));
            int o = base + tap * NICC * 8192;
            wp[o] = h;
            wp[o + nel] = l;
        }
    } else if (blk < 1824 + 4096) {
        int gid = (blk - 1824) * 256 + threadIdx.x;    // 0..1048575
        int layer = gid >> 18;
        int e = gid & 262143;
        int c5 = e & 31, k = (e >> 5) & 1023, icc = e >> 15;
        float v = a.cb[layer][(size_t)(icc * 32 + c5) * 1024 + k];
        ushort h = f2bf(v);
        ushort l = f2bf(v - bf2f(h));
        size_t o = (size_t)layer * 524288 + ((size_t)icc * 1024 + k) * 64 + c5;
        ep[o] = h; ep[o + 32] = l;
    } else {
        int b2 = blk - 1824 - 4096;
        int cc = b2 & 7, layer = b2 >> 3;
        const float* cb = a.cb[layer];
        int t = threadIdx.x;
        double d[4] = {};
        for (int c = cc * 32; c < cc * 32 + 32; ++c) {
            #pragma unroll
            for (int j = 0; j < 4; ++j) {
                double v = (double)cb[(size_t)c * 1024 + t + j * 256];
                d[j] += v * v;
            }
        }
        #pragma unroll
        for (int j = 0; j < 4; ++j) atomicAdd(en64 + layer * 1024 + t + j * 256, d[j]);
    }
}

DEV void enfin_kernel(const double* __restrict__ en64, float* __restrict__ en) {
    int gid = blockIdx.x * 256 + threadIdx.x;
    en[gid] = (float)en64[gid];
}

// ---------------------------------------------------------------- conv0_1 K-compressed: K=32 im2col (27 real), one MFMA chunk
__global__ __launch_bounds__(256) void conv01k_kernel(
        const float* __restrict__ x, const ushort* __restrict__ wp0,
        const float* __restrict__ bias, ushort* __restrict__ outs) {
    __shared__ float sX[3][10][10];
    __shared__ ushort sI[64][72];     // [px][hi 0..31 | lo 32..63]
    int t = threadIdx.x, wid = t >> 6, lane = t & 63, quad = lane >> 4, l15 = lane & 15;
    int n = blockIdx.z;
    int tIdx = blockIdx.x;
    int th0 = (tIdx >> 2) * 8, tw0 = (tIdx & 3) * 8;
    for (int i = t; i < 300; i += 256) {
        int ch = i / 100, r = i - (i / 100) * 100;
        int yy = r / 10, xx = r - (r / 10) * 10;
        int gy = th0 - 1 + yy, gx = tw0 - 1 + xx;
        float v = 0.f;
        if (gy >= 0 && gy < 32 && gx >= 0 && gx < 32) v = x[(((size_t)n * 3 + ch) * 32 + gy) * 32 + gx];
        sX[ch][yy][xx] = v;
    }
    __syncthreads();
    for (int i = t; i < 2048; i += 256) {
        int px = i >> 5, k = i & 31;
        float v = 0.f;
        if (k < 27) {
            int tap = k / 3, ch = k - tap * 3;
            int ty = tap / 3, tx = tap - ty * 3;
            v = sX[ch][(px >> 3) + ty][(px & 7) + tx];
        }
        ushort hv = f2bf(v);
        sI[px][k] = hv;
        sI[px][32 + k] = f2bf(v - bf2f(hv));
    }
    __syncthreads();
    int ocb = wid * 64;
    f4v acc[4][4];
    #pragma unroll
    for (int mt = 0; mt < 4; ++mt)
        #pragma unroll
        for (int nt = 0; nt < 4; ++nt) acc[mt][nt] = (f4v){0.f, 0.f, 0.f, 0.f};
    s8v ah[4], al[4], bh[4], bl[4];
    #pragma unroll
    for (int mt = 0; mt < 4; ++mt) {
        ah[mt] = *(const s8v*)&sI[mt * 16 + l15][quad * 8];
        al[mt] = *(const s8v*)&sI[mt * 16 + l15][32 + quad * 8];
    }
    #pragma unroll
    for (int nt = 0; nt < 4; ++nt) {
        int oc = ocb + nt * 16 + l15;
        bh[nt] = *(const s8v*)(wp0 + oc * 32 + quad * 8);
        bl[nt] = *(const s8v*)(wp0 + 8192 + oc * 32 + quad * 8);
    }
    #pragma unroll
    for (int mt = 0; mt < 4; ++mt)
        #pragma unroll
        for (int nt = 0; nt < 4; ++nt) {
            acc[mt][nt] = __builtin_amdgcn_mfma_f32_16x16x32_bf16(al[mt], bh[nt], acc[mt][nt], 0, 0, 0);
            acc[mt][nt] = __builtin_amdgcn_mfma_f32_16x16x32_bf16(ah[mt], bl[nt], acc[mt][nt], 0, 0, 0);
            acc[mt][nt] = __builtin_amdgcn_mfma_f32_16x16x32_bf16(ah[mt], bh[nt], acc[mt][nt], 0, 0, 0);
        }
    #pragma unroll
    for (int nt = 0; nt < 4; ++nt) {
        int oc = ocb + nt * 16 + l15;
        float bv = bias[oc];
        int iccg = oc >> 5, ocw = oc & 31;
        #pragma unroll
        for (int mt = 0; mt < 4; ++mt) {
            #pragma unroll
            for (int r = 0; r < 4; ++r) {
                int px = mt * 16 + quad * 4 + r;
                int y = th0 + (px >> 3), xx = tw0 + (px & 7);
                float v = fmaxf(acc[mt][nt][r] + bv, 0.f);
                ushort h = f2bf(v);
                size_t ob = ((((size_t)n * 32 + y) * 32 + xx) * 8 + iccg) * 64;
                outs[ob + ocw] = h;
                outs[ob + 32 + ocw] = f2bf(v - bf2f(h));
            }
        }
    }
}

// ---------------------------------------------------------------- VQ via MFMA, PX pixels per block
template<int PX>
DEV void vq2_kernel(const float* __restrict__ h, const float* __restrict__ cb,
                    const ushort* __restrict__ ep, const float* __restrict__ en,
                    float* __restrict__ dacc, int* __restrict__ hist,
                    ushort* __restrict__ hs, int HW) {
    const int MT = PX / 16;
    const int SUBS = 256 / PX;
    __shared__ ushort sA[8 * PX * 66];
    __shared__ unsigned long long sKey[PX][65];
    __shared__ int sKst[PX];
    __shared__ float sPart[PX][SUBS];
    __shared__ double sSum[PX];
    int t = threadIdx.x, wid = t >> 6, lane = t & 63, quad = lane >> 4, l15 = lane & 15;
    int pix0 = blockIdx.x * PX, n = pix0 / HW, s0 = pix0 % HW;
    const float* hb = h + (size_t)n * 256 * HW + s0;

    for (int i = t; i < 256 * PX; i += 256) {
        int c = i / PX, p = i % PX;
        float v = hb[(size_t)c * HW + p];
        ushort hv = f2bf(v), lv = f2bf(v - bf2f(hv));
        int a = (c >> 5) * (PX * 66) + p * 66 + (c & 31);
        sA[a] = hv; sA[a + 32] = lv;
    }
    __syncthreads();

    if (hs) {
        for (int i = t; i < PX * 32; i += 256) {
            int p = i >> 5; int rem = i & 31; int icc = rem >> 2, q = rem & 3;
            int aoff = icc * (PX * 66) + p * 66 + q * 8;
            s8v hv = *(const s8v*)&sA[aoff];
            s8v lv = *(const s8v*)&sA[aoff + 32];
            #pragma unroll
            for (int j = 0; j < 8; ++j) {
                float f = bf2f((ushort)hv[j]) + bf2f((ushort)lv[j]);
                if (f <= 0.f) { hv[j] = 0; lv[j] = 0; }
            }
            size_t ob = (((size_t)n * HW + s0 + p) * 8 + icc) * 64 + q * 8;
            *(s8v*)(hs + ob) = hv;
            *(s8v*)(hs + ob + 32) = lv;
        }
    }

    unsigned long long best[MT][4];
    #pragma unroll
    for (int mt = 0; mt < MT; ++mt)
        #pragma unroll
        for (int r = 0; r < 4; ++r) best[mt][r] = ~0ull;

    for (int kp = 0; kp < 2; ++kp) {
        f4v acc[MT][8];
        #pragma unroll
        for (int mt = 0; mt < MT; ++mt)
            #pragma unroll
            for (int nt = 0; nt < 8; ++nt) acc[mt][nt] = (f4v){0.f, 0.f, 0.f, 0.f};
        for (int icc = 0; icc < 8; ++icc) {
            #pragma unroll
            for (int ntc = 0; ntc < 2; ++ntc) {
                s8v eh[4], el[4];
                #pragma unroll
                for (int j = 0; j < 4; ++j) {
                    int k = wid * 256 + kp * 128 + (ntc * 4 + j) * 16 + l15;
                    const ushort* q = ep + ((size_t)icc * 1024 + k) * 64 + quad * 8;
                    eh[j] = *(const s8v*)q; el[j] = *(const s8v*)(q + 32);
                }
                #pragma unroll
                for (int mt = 0; mt < MT; ++mt) {
                    int a = icc * (PX * 66) + (mt * 16 + l15) * 66 + quad * 8;
                    s8v ah = *(const s8v*)&sA[a], al = *(const s8v*)&sA[a + 32];
                    #pragma unroll
                    for (int j = 0; j < 4; ++j) {
                        int nt = ntc * 4 + j;
                        acc[mt][nt] = __builtin_amdgcn_mfma_f32_16x16x32_bf16(al, eh[j], acc[mt][nt], 0, 0, 0);
                        acc[mt][nt] = __builtin_amdgcn_mfma_f32_16x16x32_bf16(ah, el[j], acc[mt][nt], 0, 0, 0);
                        acc[mt][nt] = __builtin_amdgcn_mfma_f32_16x16x32_bf16(ah, eh[j], acc[mt][nt], 0, 0, 0);
                    }
                }
            }
        }
        #pragma unroll
        for (int mt = 0; mt < MT; ++mt)
            #pragma unroll
            for (int nt = 0; nt < 8; ++nt) {
                int k = wid * 256 + kp * 128 + nt * 16 + l15;
                float ev = en[k];
                #pragma unroll
                for (int r = 0; r < 4; ++r) {
                    float s = ev - 2.f * acc[mt][nt][r];
                    unsigned ub = __float_as_uint(s);
                    ub = ((int)ub < 0) ? ~ub : (ub | 0x80000000u);
                    unsigned long long key = ((unsigned long long)ub << 32) | (unsigned)k;
                    if (key < best[mt][r]) best[mt][r] = key;
                }
            }
    }
    #pragma unroll
    for (int mt = 0; mt < MT; ++mt)
        #pragma unroll
        for (int r = 0; r < 4; ++r) {
            int p = mt * 16 + quad * 4 + r;
            sKey[p][wid * 16 + l15] = best[mt][r];
        }
    __syncthreads();
    if (t < PX) {
        unsigned long long m = ~0ull;
        for (int j = 0; j < 64; ++j) { unsigned long long v = sKey[t][j]; if (v < m) m = v; }
        sKst[t] = (int)(unsigned)(m & 0xFFFFFFFFu);
    }
    __syncthreads();
    {
        int p = t % PX, sub = t / PX;
        int ks = sKst[p];
        const float* ec = cb + ks;
        float d = 0.f;
        for (int c = sub * PX; c < sub * PX + PX; ++c) {
            float xv = hb[(size_t)c * HW + p];
            float evv = ec[(size_t)c * 1024];
            float df = xv - evv;
            d += df * df;
        }
        sPart[p][sub] = d;
    }
    __syncthreads();
    if (t < PX) {
        float s = 0.f;
        for (int j = 0; j < SUBS; ++j) s += sPart[t][j];
        sSum[t] = (double)s;
        if (hist) atomicAdd(hist + sKst[t], 1);
    }
    __syncthreads();
    if (t == 0) {
        double s = 0.0;
        for (int i = 0; i < PX; ++i) s += sSum[i];
        atomicAdd(dacc + n, (float)s);
    }
}

// ---------------------------------------------------------------- 16x16x32 MFMA implicit-GEMM 3x3 conv, pad 1
// INS: register-prefetch + LDS ping-pong double-buffer; one barrier per icc.
template<int ST, int NW, int NTW, int NICC, bool RELU, bool POOL, bool RES, bool INS, bool OUTS, bool SC0>
__global__ __launch_bounds__(NW * 64) void conv_mfma(
        const float* __restrict__ in, const ushort* __restrict__ ins,
        const ushort* __restrict__ wp, const float* __restrict__ bias,
        const float* __restrict__ res, float* __restrict__ out,
        ushort* __restrict__ outs, int C, int H,
        const float* __restrict__ scw, const float* __restrict__ scb,
        const double* __restrict__ un2) {
    const int MT = ST * 4;
    const int PLANE = NICC * 73728;
    const int SASZ = ST * 100 * 72;
    const int NITER = (ST * 100 * 8 + NW * 64 - 1) / (NW * 64);
    __shared__ ushort sA[(INS ? 2 : 1) * SASZ];
    __shared__ float sSC[3][16];
    int t = threadIdx.x;
    int wid = t >> 6, lane = t & 63, quad = lane >> 4, l15 = lane & 15;
    int n = blockIdx.z;
    int ocb = blockIdx.y * (NW * NTW * 16) + wid * (NTW * 16);
    int tpr = H >> 3;
    int tIdx0 = blockIdx.x * ST;

    int abase[MT];
    #pragma unroll
    for (int mt = 0; mt < MT; ++mt) {
        int m64 = (mt & 3) * 16 + l15;
        abase[mt] = (((mt >> 2) * 100 + (m64 >> 3) * 10 + (m64 & 7)) * 72) + quad * 8;
    }

    unsigned gofs[INS ? NITER : 1];
    s8v pref[INS ? NITER : 1];
    if (INS) {
        #pragma unroll
        for (int it = 0; it < NITER; ++it) {
            int i = t + it * NW * 64;
            gofs[it] = 0xFFFFFFFFu;
            if (i < ST * 100 * 8) {
                int pg = i >> 3, part = i & 7;
                int tile = pg / 100, pos = pg - tile * 100;
                int tIdx = tIdx0 + tile;
                int th0 = (tIdx / tpr) * 8, tw0 = (tIdx % tpr) * 8;
                int gy = th0 - 1 + pos / 10, gx = tw0 - 1 + (pos % 10);
                if (gy >= 0 && gy < H && gx >= 0 && gx < H)
                    gofs[it] = (unsigned)((((n * H + gy) * H + gx) * 8) * 64 + part * 8);
            }
        }
        #pragma unroll
        for (int it = 0; it < NITER; ++it)
            pref[it] = (gofs[it] != 0xFFFFFFFFu) ? *(const s8v*)(ins + gofs[it])
                                                 : (s8v){0, 0, 0, 0, 0, 0, 0, 0};
        #pragma unroll
        for (int it = 0; it < NITER; ++it) {
            int i = t + it * NW * 64;
            if (i < ST * 100 * 8) *(s8v*)(&sA[(i >> 3) * 72 + (i & 7) * 8]) = pref[it];
        }
        if (NICC > 1) {
            #pragma unroll
            for (int it = 0; it < NITER; ++it)
                pref[it] = (gofs[it] != 0xFFFFFFFFu) ? *(const s8v*)(ins + gofs[it] + 64)
                                                     : (s8v){0, 0, 0, 0, 0, 0, 0, 0};
        }
        __syncthreads();
    }

    f4v acc[MT][NTW];
    #pragma unroll
    for (int mt = 0; mt < MT; ++mt)
        #pragma unroll
        for (int nt = 0; nt < NTW; ++nt)
            acc[mt][nt] = (f4v){0.f, 0.f, 0.f, 0.f};

    for (int icc = 0; icc < NICC; ++icc) {
        int bufbase = INS ? (icc & 1) * SASZ : 0;
        if (INS) {
            if (icc + 1 < NICC) {
                int nb = ((icc + 1) & 1) * SASZ;
                #pragma unroll
                for (int it = 0; it < NITER; ++it) {
                    int i = t + it * NW * 64;
                    if (i < ST * 100 * 8) *(s8v*)(&sA[nb + (i >> 3) * 72 + (i & 7) * 8]) = pref[it];
                }
                if (icc + 2 < NICC) {
                    #pragma unroll
                    for (int it = 0; it < NITER; ++it)
                        pref[it] = (gofs[it] != 0xFFFFFFFFu) ? *(const s8v*)(ins + gofs[it] + (unsigned)(icc + 2) * 64)
                                                             : (s8v){0, 0, 0, 0, 0, 0, 0, 0};
                }
            }
        } else {
            __syncthreads();
            for (int i = t; i < ST * 100 * 32; i += NW * 64) {
                int ic = i / (ST * 100);
                int rr = i - ic * (ST * 100);
                int tile = rr / 100, pos = rr - (rr / 100) * 100;
                int tIdx = tIdx0 + tile;
                int th0 = (tIdx / tpr) * 8, tw0 = (tIdx % tpr) * 8;
                int gy = th0 - 1 + pos / 10, gx = tw0 - 1 + (pos % 10);
                int gic = icc * 32 + ic;
                ushort hv = 0, lv = 0;
                if (gic < C && gy >= 0 && gy < H && gx >= 0 && gx < H) {
                    float v = in[(((size_t)n * C + gic) * H + gy) * H + gx];
                    if (RELU) v = fmaxf(v, 0.f);
                    hv = f2bf(v);
                    lv = f2bf(v - bf2f(hv));
                }
                int si = (tile * 100 + pos) * 72 + ic;
                sA[si] = hv; sA[si + 32] = lv;
            }
            __syncthreads();
        }

        s8v bh[2][NTW], bl[2][NTW];
        {
            size_t wb = (size_t)icc * 8192;
            #pragma unroll
            for (int nt = 0; nt < NTW; ++nt) {
                size_t wo = wb + (size_t)(ocb + nt * 16 + l15) * 32 + quad * 8;
                bh[0][nt] = *(const s8v*)(wp + wo);
                bl[0][nt] = *(const s8v*)(wp + PLANE + wo);
            }
        }
        #pragma unroll
        for (int tap = 0; tap < 9; ++tap) {
            int cb = tap & 1;
            if (tap < 8) {
                size_t wb = (size_t)((tap + 1) * NICC + icc) * 8192;
                #pragma unroll
                for (int nt = 0; nt < NTW; ++nt) {
                    size_t wo = wb + (size_t)(ocb + nt * 16 + l15) * 32 + quad * 8;
                    bh[cb ^ 1][nt] = *(const s8v*)(wp + wo);
                    bl[cb ^ 1][nt] = *(const s8v*)(wp + PLANE + wo);
                }
            }
            int toff = ((tap / 3) * 10 + (tap % 3)) * 72;
            #pragma unroll
            for (int mt = 0; mt < MT; ++mt) {
                s8v ah = *(const s8v*)(&sA[bufbase + abase[mt] + toff]);
                s8v al = *(const s8v*)(&sA[bufbase + abase[mt] + toff + 32]);
                #pragma unroll
                for (int nt = 0; nt < NTW; ++nt) {
                    acc[mt][nt] = __builtin_amdgcn_mfma_f32_16x16x32_bf16(al, bh[cb][nt], acc[mt][nt], 0, 0, 0);
                    acc[mt][nt] = __builtin_amdgcn_mfma_f32_16x16x32_bf16(ah, bl[cb][nt], acc[mt][nt], 0, 0, 0);
                    acc[mt][nt] = __builtin_amdgcn_mfma_f32_16x16x32_bf16(ah, bh[cb][nt], acc[mt][nt], 0, 0, 0);
                }
            }
        }
        if (INS && icc + 1 < NICC) __syncthreads();
    }

    if (SC0) {
        __syncthreads();
        if (t < 48) {
            int ic = t >> 4, p = t & 15;
            int py = p >> 2, px = p & 3;
            int th0 = (tIdx0 / tpr) * 8, tw0 = (tIdx0 % tpr) * 8;
            const float* xb = in + (((size_t)(n * 3 + ic)) * 32 + th0 + 2 * py) * 32 + tw0 + 2 * px;
            sSC[ic][p] = 0.25f * (xb[0] + xb[1] + xb[32] + xb[33]);
        }
        __syncthreads();
    }

    #pragma unroll
    for (int nt = 0; nt < NTW; ++nt) {
        int oc = ocb + nt * 16 + l15;
        float bv = bias[oc];
        #pragma unroll
        for (int mt = 0; mt < MT; ++mt) {
            int tIdx = tIdx0 + (mt >> 2);
            int th0 = (tIdx / tpr) * 8, tw0 = (tIdx % tpr) * 8;
            if (POOL) {
                float s01 = acc[mt][nt][0] + acc[mt][nt][1];
                float s23 = acc[mt][nt][2] + acc[mt][nt][3];
                float o01 = s01 + __shfl_down(s01, 32, 64);
                float o23 = s23 + __shfl_down(s23, 32, 64);
                if (quad < 2) {
                    int Ho = H >> 1;
                    int oy = (th0 >> 1) + (mt & 3);
                    int ox = (tw0 >> 1) + quad * 2;
                    size_t ob = ((size_t)(n * 256 + oc) * Ho + oy) * Ho;
                    float v0 = 0.25f * o01 + bv;
                    float v1 = 0.25f * o23 + bv;
                    if (SC0) {
                        int p0 = (mt & 3) * 4 + quad * 2;
                        float scale = 1.f / sig_of(un2[2]);
                        float sa0 = scb[oc], sa1 = scb[oc];
                        #pragma unroll
                        for (int ic = 0; ic < 3; ++ic) {
                            float wv = scw[oc * 3 + ic] * scale;
                            sa0 += sSC[ic][p0] * wv;
                            sa1 += sSC[ic][p0 + 1] * wv;
                        }
                        v0 += sa0;
                        v1 += sa1;
                    }
                    out[ob + ox] = v0;
                    out[ob + ox + 1] = v1;
                }
            } else if (OUTS) {
                int iccg = oc >> 5, ocw = oc & 31;
                #pragma unroll
                for (int r = 0; r < 4; ++r) {
                    int p16 = quad * 4 + r;
                    int y = th0 + (mt & 3) * 2 + (p16 >> 3);
                    int x = tw0 + (p16 & 7);
                    float v = fmaxf(acc[mt][nt][r] + bv, 0.f);
                    ushort h = f2bf(v);
                    size_t ob = ((((size_t)n * H + y) * H + x) * 8 + iccg) * 64;
                    outs[ob + ocw] = h;
                    outs[ob + 32 + ocw] = f2bf(v - bf2f(h));
                }
            } else {
                #pragma unroll
                for (int r = 0; r < 4; ++r) {
                    int p16 = quad * 4 + r;
                    int y = th0 + (mt & 3) * 2 + (p16 >> 3);
                    int x = tw0 + (p16 & 7);
                    size_t oi = (((size_t)(n * 256 + oc)) * H + y) * H + x;
                    float v = acc[mt][nt][r] + bv;
                    if (RES) v += res[oi];
                    out[oi] = v;
                }
            }
        }
    }
}

// ---------------------------------------------------------------- block-1 shortcut: h2 += conv1x1(pool2(h1)) + b
DEV void sc1_kernel(const float* __restrict__ h1, const float* __restrict__ wsc,
                    const float* __restrict__ bsc, const double* __restrict__ unorm2,
                    float* __restrict__ h2) {
    __shared__ float sP[64][64];
    __shared__ float sWs[64][65];
    int t = threadIdx.x;
    int n = blockIdx.x, ocb = blockIdx.y * 64;
    int ocg = t & 15, pgr = t >> 4;
    float scale = 1.f / sig_of(unorm2[5]);
    float acc[4][4] = {};
    for (int c0 = 0; c0 < 256; c0 += 64) {
        __syncthreads();
        for (int i = t; i < 4096; i += 256) {
            int ic = i >> 6, p = i & 63;
            int oh = p >> 3, ow = p & 7;
            const float* hb = h1 + (((size_t)(n * 256 + c0 + ic)) * 16 + oh * 2) * 16 + ow * 2;
            sP[ic][p] = 0.25f * (hb[0] + hb[1] + hb[16] + hb[17]);
            int oc = i >> 6, ic2 = i & 63;
            sWs[oc][ic2] = wsc[(size_t)(ocb + oc) * 256 + c0 + ic2] * scale;
        }
        __syncthreads();
        for (int ic = 0; ic < 64; ++ic) {
            float pv[4];
            #pragma unroll
            for (int q = 0; q < 4; ++q) pv[q] = sP[ic][pgr * 4 + q];
            #pragma unroll
            for (int j = 0; j < 4; ++j) {
                float wv = sWs[ocg + 16 * j][ic];
                #pragma unroll
                for (int q = 0; q < 4; ++q) acc[j][q] += wv * pv[q];
            }
        }
    }
    #pragma unroll
    for (int j = 0; j < 4; ++j) {
        int oc = ocb + ocg + 16 * j;
        float bv = bsc[oc];
        #pragma unroll
        for (int q = 0; q < 4; ++q) {
            size_t oi = ((size_t)(n * 256 + oc)) * 64 + pgr * 4 + q;
            h2[oi] += acc[j][q] + bv;
        }
    }
}

// ---------------------------------------------------------------- head + ppl (merged)
DEV void headppl_kernel(const float* __restrict__ h4, const float* __restrict__ lin_w,
                        const float* __restrict__ lin_b, const float* __restrict__ emb_w,
                        const int* __restrict__ y, const double* __restrict__ unorm2,
                        const float* __restrict__ dacc, const int* __restrict__ hist,
                        float* __restrict__ out) {
    __shared__ double r1[256], r2[256];
    int b = blockIdx.x, t = threadIdx.x;
    const float* hb = h4 + ((size_t)b * 256 + t) * 64;
    float s = 0.f;
    #pragma unroll 4
    for (int i = 0; i < 64; ++i) s += fmaxf(hb[i], 0.f);
    int yb = y[b];
    r1[t] = (double)s * (double)lin_w[t];
    r2[t] = (double)s * (double)emb_w[(size_t)yb * 256 + t];
    __syncthreads();
    for (int st = 128; st > 0; st >>= 1) { if (t < st) { r1[t] += r1[t + st]; r2[t] += r2[t + st]; } __syncthreads(); }
    if (t == 0) {
        out[b] = (float)(r1[0] / (double)sig_of(unorm2[10]) + (double)lin_b[0] + r2[0] / (double)sig_of(unorm2[11]));
        out[64 + b] = (float)(0.5 * ((double)dacc[b] * (1.0 / 65536.0)
                              + ((double)dacc[64 + b] + (double)dacc[128 + b] + (double)dacc[192 + b]) * (1.0 / 16384.0)));
    }
    if (b == 0) {
        __syncthreads();
        double ps = 0.0;
        for (int k = t; k < 1024; k += 256) {
            double p = (double)hist[k] * (1.0 / 4096.0);
            ps += p * log(p + 1e-10);
        }
        r1[t] = ps; __syncthreads();
        for (int st = 128; st > 0; st >>= 1) { if (t < st) r1[t] += r1[t + st]; __syncthreads(); }
        if (t == 0) out[128] = (float)exp(-r1[0]);
    }
}

// ---------------------------------------------------------------- launch
extern "C" void kernel_launch(void* const* d_in, const int* in_sizes, int n_in,
                              void* d_out, int out_size, void* d_ws, size_t ws_size,
                              hipStream_t stream) {
    (void)in_sizes; (void)n_in; (void)out_size; (void)ws_size;
    const float* x      = (const float*)d_in[0];
    const int*   y      = (const int*)  d_in[1];
    const float* b0_w1  = (const float*)d_in[2];
    const float* b0_b1  = (const float*)d_in[3];
    const float* b0_w2  = (const float*)d_in[4];
    const float* b0_b2  = (const float*)d_in[5];
    const float* b0_wsc = (const float*)d_in[6];
    const float* b0_bsc = (const float*)d_in[7];
    const float* b1_w1  = (const float*)d_in[8];
    const float* b1_b1  = (const float*)d_in[9];
    const float* b1_w2  = (const float*)d_in[10];
    const float* b1_b2  = (const float*)d_in[11];
    const float* b1_wsc = (const float*)d_in[12];
    const float* b1_bsc = (const float*)d_in[13];
    const float* b2_w1  = (const float*)d_in[14];
    const float* b2_b1  = (const float*)d_in[15];
    const float* b2_w2  = (const float*)d_in[16];
    const float* b2_b2  = (const float*)d_in[17];
    const float* b3_w1  = (const float*)d_in[18];
    const float* b3_b1  = (const float*)d_in[19];
    const float* b3_w2  = (const float*)d_in[20];
    const float* b3_b2  = (const float*)d_in[21];
    const float* cb0    = (const float*)d_in[22];
    const float* cb1    = (const float*)d_in[23];
    const float* cb2    = (const float*)d_in[24];
    const float* cb3    = (const float*)d_in[25];
    const float* lin_w  = (const float*)d_in[26];
    const float* lin_b  = (const float*)d_in[27];
    const float* emb_w  = (const float*)d_in[28];
    float* out = (float*)d_out;

    // ---- workspace map (float indices) ----
    float* wsf  = (float*)d_ws;
    float* dacc = wsf + 16;                                      // [16,272)
    double* vnorm2 = (double*)(wsf + 512);                       // [512,536)
    double* unorm2 = (double*)(wsf + 544);                       // [544,568)
    int*   hist = (int*)(wsf + 1296);                            // [1296,2320) ints
    double* en64 = (double*)(wsf + 2560);                        // [2560,10752)
    float* en   = wsf + 10752;                                   // [10752,14848)
    ushort* Aus  = (ushort*)(wsf + 65536);                       // [65536,16842752) (dead after conv0_2)
    ushort* tbus = (ushort*)(wsf + 65536);                       // aliases dead A
    ushort* t2us = (ushort*)(wsf + 4259840);
    ushort* h1s  = (ushort*)(wsf + 5308416);
    ushort* h2s  = (ushort*)(wsf + 9502720);
    ushort* h3s  = (ushort*)(wsf + 10551296);
    float* h1 = wsf + 16842752;
    float* h2 = h1 + 4194304;
    float* h3 = h2 + 1048576;
    float* h4 = h3 + 1048576;
    ushort* wp = (ushort*)(wsf + 24182784);                      // ends f 28385280
    double* vbufraw = (double*)(wsf + 28385280);                 // ends f 28440576
    ushort* ep = (ushort*)(wsf + 28440576);                      // ends f 30537728 (116.5 MB)

    hipMemsetAsync(wsf, 0, 10752 * sizeof(float), stream);
    hipMemsetAsync(vbufraw, 0, 27648 * sizeof(double), stream);

    SnMeta sm;
    const float* sw[12] = {b0_w1, b0_w2, b0_wsc, b1_w1, b1_w2, b1_wsc,
                           b2_w1, b2_w2, b3_w1, b3_w2, lin_w, emb_w};
    int sO[12] = {256, 256, 256, 256, 256, 256, 256, 256, 256, 256, 1, 100};
    int sM[12] = {27, 2304, 3, 2304, 2304, 256, 2304, 2304, 2304, 2304, 256, 256};
    for (int i = 0; i < 12; ++i) { sm.w[i] = sw[i]; sm.O[i] = sO[i]; sm.M[i] = sM[i]; }
    SnRMap rp;
    {
        int bi = 0;
        for (int i = 0; i < 12; ++i) {
            int nb = (sO[i] + 31) / 32;
            for (int j = 0; j < nb; ++j) { rp.mat[bi] = (short)i; rp.row0[bi] = (short)(j * 32); ++bi; }
        }
    }
    snv2_kernel<<<85, 256, 0, stream>>>(sm, rp, vbufraw);
    snn_kernel<<<12, 256, 0, stream>>>(sm, vbufraw, vnorm2);
    snu_kernel<<<666, 256, 0, stream>>>(sm, vbufraw, vnorm2, unorm2);

    PrepArgs pa;
    const float* pw[8] = {b0_w1, b0_w2, b1_w1, b1_w2, b2_w1, b2_w2, b3_w1, b3_w2};
    int pC[8]   = {3, 256, 256, 256, 256, 256, 256, 256};
    int pS[8]   = {0, 1, 3, 4, 6, 7, 8, 9};
    int pOff[8] = {0, 147456, 1327104, 2506752, 3686400, 4866048, 6045696, 7225344};
    int pN[8]   = {73728, 589824, 589824, 589824, 589824, 589824, 589824, 589824};
    for (int i = 0; i < 8; ++i) { pa.w[i] = pw[i]; pa.C[i] = pC[i]; pa.sigidx[i] = pS[i]; pa.outoff[i] = pOff[i]; pa.nel[i] = pN[i]; }
    pa.cb[0] = cb0; pa.cb[1] = cb1; pa.cb[2] = cb2; pa.cb[3] = cb3;
    prep_all_kernel<<<5952, 256, 0, stream>>>(pa, unorm2, wp, ep, en64);
    enfin_kernel<<<16, 256, 0, stream>>>(en64, en);

    // block 0: conv0_1 K-compressed; conv0_2 with fused sc0
    conv01k_kernel<<<dim3(16, 1, 64), 256, 0, stream>>>(x, wp, b0_b1, Aus);
    conv_mfma<1, 4, 2, 8, false, true, false, true, false, true><<<dim3(16, 2, 64), 256, 0, stream>>>(
        x, Aus, wp + 147456, b0_b2, nullptr, h1, nullptr, 256, 32, b0_wsc, b0_bsc, unorm2);
    vq2_kernel<32><<<512, 256, 0, stream>>>(h1, cb0, ep + 0, en + 0, dacc + 0, nullptr, h1s, 256);

    // block 1
    conv_mfma<1, 4, 1, 8, false, false, false, true, true, false><<<dim3(4, 4, 64), 256, 0, stream>>>(
        nullptr, h1s, wp + 1327104, b1_b1, nullptr, nullptr, tbus, 256, 16, nullptr, nullptr, nullptr);
    conv_mfma<1, 4, 1, 8, false, true, false, true, false, false><<<dim3(4, 4, 64), 256, 0, stream>>>(
        nullptr, tbus, wp + 2506752, b1_b2, nullptr, h2, nullptr, 256, 16, nullptr, nullptr, nullptr);
    sc1_kernel<<<dim3(64, 4), 256, 0, stream>>>(h1, b1_wsc, b1_bsc, unorm2, h2);
    vq2_kernel<16><<<256, 256, 0, stream>>>(h2, cb1, ep + 524288, en + 1024, dacc + 64, nullptr, h2s, 64);

    // block 2
    conv_mfma<1, 2, 1, 8, false, false, false, true, true, false><<<dim3(1, 8, 64), 128, 0, stream>>>(
        nullptr, h2s, wp + 3686400, b2_b1, nullptr, nullptr, t2us, 256, 8, nullptr, nullptr, nullptr);
    conv_mfma<1, 2, 1, 8, false, false, true, true, false, false><<<dim3(1, 8, 64), 128, 0, stream>>>(
        nullptr, t2us, wp + 4866048, b2_b2, h2, h3, nullptr, 256, 8, nullptr, nullptr, nullptr);
    vq2_kernel<16><<<256, 256, 0, stream>>>(h3, cb2, ep + 1048576, en + 2048, dacc + 128, nullptr, h3s, 64);

    // block 3
    conv_mfma<1, 2, 1, 8, false, false, false, true, true, false><<<dim3(1, 8, 64), 128, 0, stream>>>(
        nullptr, h3s, wp + 6045696, b3_b1, nullptr, nullptr, t2us, 256, 8, nullptr, nullptr, nullptr);
    conv_mfma<1, 2, 1, 8, false, false, true, true, false, false><<<dim3(1, 8, 64), 128, 0, stream>>>(
        nullptr, t2us, wp + 7225344, b3_b2, h3, h4, nullptr, 256, 8, nullptr, nullptr, nullptr);
    vq2_kernel<16><<<256, 256, 0, stream>>>(h4, cb3, ep + 1572864, en + 3072, dacc + 192, hist, nullptr, 64);

    headppl_kernel<<<64, 256, 0, stream>>>(h4, lin_w, lin_b, emb_w, y, unorm2, dacc, hist, out);
}